// Round 1
// baseline (1286.159 us; speedup 1.0000x reference)
//
#include <hip/hip_runtime.h>
#include <math.h>

#define DD 128

__device__ __forceinline__ float mishf(float x) {
    // mish(x) = x*tanh(softplus(x)) = x*(e^2x+2e^x)/(e^2x+2e^x+2), clamped for overflow
    float e = __expf(fminf(x, 15.0f));
    float n = e * (e + 2.0f);
    return x * (n / (n + 2.0f));
}

// ---------------- GEMM: C[M,128] = ACT( A[M,128]@W[128,128] + rs_i*X_ij + bv_i*bias_j )
// ACT: 0 none, 1 mish, 2 mish(mish)
template<int ACT, bool HAS_X, bool HAS_RS, bool HAS_BIAS, bool HAS_BV>
__global__ __launch_bounds__(256)
void gemm128(const float* __restrict__ A, const float* __restrict__ W,
             float* __restrict__ C, int M,
             const float* __restrict__ X, const float* __restrict__ rs,
             const float* __restrict__ bias, const int* __restrict__ bv)
{
    __shared__ float As[128][33];   // +1 pad: compute reads stride-33 rows -> banks spread
    __shared__ float Ws[32][128];
    const int tid = threadIdx.x;
    const int tx = tid & 15;        // 16 col-groups * 8 cols = 128
    const int ty = tid >> 4;        // 16 row-groups * 8 rows = 128
    const int rowBase = blockIdx.x * 128;

    float acc[8][8];
#pragma unroll
    for (int i = 0; i < 8; i++)
#pragma unroll
        for (int j = 0; j < 8; j++) acc[i][j] = 0.0f;

    for (int k0 = 0; k0 < 128; k0 += 32) {
#pragma unroll
        for (int i = 0; i < 4; i++) {           // A tile 128x32 = 1024 float4
            int idx4 = tid + i * 256;
            int r = idx4 >> 3;
            int c4 = idx4 & 7;
            int row = rowBase + r;
            float4 v = make_float4(0.f, 0.f, 0.f, 0.f);
            if (row < M) v = *(const float4*)(A + (size_t)row * DD + k0 + c4 * 4);
            As[r][c4 * 4 + 0] = v.x;
            As[r][c4 * 4 + 1] = v.y;
            As[r][c4 * 4 + 2] = v.z;
            As[r][c4 * 4 + 3] = v.w;
        }
#pragma unroll
        for (int i = 0; i < 4; i++) {           // W tile 32x128 = 1024 float4
            int idx4 = tid + i * 256;
            int r = idx4 >> 5;
            int c4 = idx4 & 31;
            float4 v = *(const float4*)(W + (size_t)(k0 + r) * DD + c4 * 4);
            *(float4*)(&Ws[r][c4 * 4]) = v;
        }
        __syncthreads();
#pragma unroll 4
        for (int k = 0; k < 32; k++) {
            float a[8], w[8];
#pragma unroll
            for (int i = 0; i < 8; i++) a[i] = As[ty * 8 + i][k];
            *(float4*)(&w[0]) = *(const float4*)(&Ws[k][tx * 8]);
            *(float4*)(&w[4]) = *(const float4*)(&Ws[k][tx * 8 + 4]);
#pragma unroll
            for (int i = 0; i < 8; i++)
#pragma unroll
                for (int j = 0; j < 8; j++)
                    acc[i][j] += a[i] * w[j];
        }
        __syncthreads();
    }

#pragma unroll
    for (int i = 0; i < 8; i++) {
        int row = rowBase + ty * 8 + i;
        if (row >= M) continue;
        float rsv = HAS_RS ? rs[row] : 1.0f;
        float bvf = HAS_BV ? (float)bv[row] : 1.0f;
#pragma unroll
        for (int j8 = 0; j8 < 2; j8++) {
            int col = tx * 8 + j8 * 4;
            float4 v;
            v.x = acc[i][j8 * 4 + 0]; v.y = acc[i][j8 * 4 + 1];
            v.z = acc[i][j8 * 4 + 2]; v.w = acc[i][j8 * 4 + 3];
            if (HAS_X) {
                float4 xv = *(const float4*)(X + (size_t)row * DD + col);
                v.x += rsv * xv.x; v.y += rsv * xv.y; v.z += rsv * xv.z; v.w += rsv * xv.w;
            }
            if (HAS_BIAS) {
                float4 bb = *(const float4*)(bias + col);
                v.x += bvf * bb.x; v.y += bvf * bb.y; v.z += bvf * bb.z; v.w += bvf * bb.w;
            }
            if (ACT >= 1) { v.x = mishf(v.x); v.y = mishf(v.y); v.z = mishf(v.z); v.w = mishf(v.w); }
            if (ACT == 2) { v.x = mishf(v.x); v.y = mishf(v.y); v.z = mishf(v.z); v.w = mishf(v.w); }
            *(float4*)(C + (size_t)row * DD + col) = v;
        }
    }
}

// ---------------- CSR build (counting sort by dst) ----------------
__global__ __launch_bounds__(256) void hist_kernel(const int* __restrict__ ei, int* __restrict__ deg, int E)
{
    int e = blockIdx.x * 256 + threadIdx.x;
    if (e < E) atomicAdd(&deg[ei[E + e]], 1);
}

__global__ __launch_bounds__(1024) void scan_kernel(const int* __restrict__ deg,
                                                    int* __restrict__ rowptr,
                                                    int* __restrict__ cursor, int N)
{
    __shared__ int sums[1024];
    int t = threadIdx.x;
    int CH = (N + 1023) / 1024;
    int base = t * CH;
    int local = 0;
    for (int i = 0; i < CH; i++) {
        int idx = base + i;
        if (idx < N) local += deg[idx];
    }
    sums[t] = local;
    __syncthreads();
    for (int off = 1; off < 1024; off <<= 1) {
        int v = sums[t];
        int u = (t >= off) ? sums[t - off] : 0;
        __syncthreads();
        sums[t] = v + u;
        __syncthreads();
    }
    int run = (t == 0) ? 0 : sums[t - 1];
    for (int i = 0; i < CH; i++) {
        int idx = base + i;
        if (idx < N) {
            rowptr[idx] = run;
            cursor[idx] = run;
            run += deg[idx];
        }
    }
    if (t == 1023) rowptr[N] = sums[1023];
}

__global__ __launch_bounds__(256) void scatter_kernel(
    const int* __restrict__ ei, const int* __restrict__ bond,
    const float* __restrict__ conv_w, const float* __restrict__ conv_b,
    const float* __restrict__ coords, int* __restrict__ cursor,
    int* __restrict__ csr_src, float* __restrict__ csr_w, float* __restrict__ csr_d2, int E)
{
    int e = blockIdx.x * 256 + threadIdx.x;
    if (e >= E) return;
    int src = ei[e], dst = ei[E + e];
    int pos = atomicAdd(&cursor[dst], 1);
    csr_src[pos] = src;
    csr_w[pos] = conv_w[bond[e]] + conv_b[0];
    float dx = coords[src * 3 + 0] - coords[dst * 3 + 0];
    float dy = coords[src * 3 + 1] - coords[dst * 3 + 1];
    float dz = coords[src * 3 + 2] - coords[dst * 3 + 2];
    csr_d2[pos] = dx * dx + dy * dy + dz * dz;
}

// ---------------- per-node edge aggregation: one wave per node ----------------
__global__ __launch_bounds__(256) void edge_agg(
    const float* __restrict__ At, const float* __restrict__ Asrc,
    const float* __restrict__ Bt, const float* __restrict__ Bs,
    const float* __restrict__ x,
    const int* __restrict__ rowptr, const int* __restrict__ csr_src,
    const float* __restrict__ csr_w, const float* __restrict__ csr_d2,
    const float* __restrict__ b_nb, const float* __restrict__ b_el,
    float* __restrict__ Pn, float* __restrict__ Pe, float* __restrict__ z,
    float* __restrict__ s_arr, int N)
{
    int wave = threadIdx.x >> 6;
    int lane = threadIdx.x & 63;
    int node = blockIdx.x * 4 + wave;
    if (node >= N) return;
    int c0 = lane * 2;                       // 2 of the 128 cols per lane
    float2 at = *(const float2*)(At + (size_t)node * DD + c0);
    float2 bt = *(const float2*)(Bt + (size_t)node * DD + c0);
    float2 bn = *(const float2*)(b_nb + c0);
    float2 be = *(const float2*)(b_el + c0);
    float2 accn = make_float2(0.f, 0.f), acce = make_float2(0.f, 0.f), accz = make_float2(0.f, 0.f);
    float ssum = 0.f;
    int beg = rowptr[node], end = rowptr[node + 1];
    for (int k = beg; k < end; k++) {
        int j = csr_src[k];
        float w = csr_w[k];
        float d2 = csr_d2[k];
        float2 av = *(const float2*)(Asrc + (size_t)j * DD + c0);
        accn.x += mishf(at.x + av.x + bn.x);
        accn.y += mishf(at.y + av.y + bn.y);
        float2 bv = *(const float2*)(Bs + (size_t)j * DD + c0);
        acce.x += mishf(w * (bt.x + bv.x) + be.x);
        acce.y += mishf(w * (bt.y + bv.y) + be.y);
        float2 xv = *(const float2*)(x + (size_t)j * DD + c0);
        accz.x += d2 * xv.x;
        accz.y += d2 * xv.y;
        ssum += d2;
    }
    *(float2*)(Pn + (size_t)node * DD + c0) = accn;
    *(float2*)(Pe + (size_t)node * DD + c0) = acce;
    *(float2*)(z + (size_t)node * DD + c0) = accz;
    if (lane == 0) s_arr[node] = ssum;
}

// ---------------- softmax over 3 paths + weighted combine ----------------
__device__ __forceinline__ float att3(float x1, float x2, float x3, float g1, float g2, float g3)
{
    float m = fmaxf(fmaxf(x1, x2), x3);
    float p1 = __expf(x1 - m), p2 = __expf(x2 - m), p3 = __expf(x3 - m);
    return (p1 * g1 + p2 * g2 + p3 * g3) / (p1 + p2 + p3);
}

__global__ __launch_bounds__(256) void att_kernel(
    const float* __restrict__ e1, const float* __restrict__ e2, const float* __restrict__ e3,
    const float* __restrict__ f1, const float* __restrict__ f2, const float* __restrict__ f3,
    float* __restrict__ out, size_t total4)
{
    size_t idx = (size_t)blockIdx.x * 256 + threadIdx.x;
    if (idx >= total4) return;
    size_t off = idx * 4;
    float4 a = *(const float4*)(e1 + off);
    float4 b = *(const float4*)(e2 + off);
    float4 c = *(const float4*)(e3 + off);
    float4 g = *(const float4*)(f1 + off);
    float4 h = *(const float4*)(f2 + off);
    float4 k = *(const float4*)(f3 + off);
    float4 o;
    o.x = att3(a.x, b.x, c.x, g.x, h.x, k.x);
    o.y = att3(a.y, b.y, c.y, g.y, h.y, k.y);
    o.z = att3(a.z, b.z, c.z, g.z, h.z, k.z);
    o.w = att3(a.w, b.w, c.w, g.w, h.w, k.w);
    *(float4*)(out + off) = o;
}

// ---------------- batchnorm ----------------
__global__ __launch_bounds__(256) void bn_stats(const float* __restrict__ h, float* __restrict__ sums, int N)
{
    int t = threadIdx.x;
    int col = t & 127;
    float s = 0.f, sq = 0.f;
    for (int r = blockIdx.x * 2 + (t >> 7); r < N; r += gridDim.x * 2) {
        float v = h[(size_t)r * DD + col];
        s += v; sq += v * v;
    }
    __shared__ float sh[256];
    sh[t] = s; __syncthreads();
    float s2 = (t < 128) ? (sh[t] + sh[t + 128]) : 0.f;
    __syncthreads();
    sh[t] = sq; __syncthreads();
    if (t < 128) {
        float q2 = sh[t] + sh[t + 128];
        atomicAdd(&sums[t], s2);
        atomicAdd(&sums[128 + t], q2);
    }
}

__global__ void bn_finalize(const float* __restrict__ sums, const float* __restrict__ gamma,
                            const float* __restrict__ beta, float* __restrict__ scale,
                            float* __restrict__ shift, float n_inv)
{
    int c = threadIdx.x;
    float mean = sums[c] * n_inv;
    float var = sums[128 + c] * n_inv - mean * mean;
    float inv = rsqrtf(var + 1e-5f);
    float sc = gamma[c] * inv;
    scale[c] = sc;
    shift[c] = beta[c] - mean * sc;
}

__global__ __launch_bounds__(256) void bn_apply(float* __restrict__ h, const float* __restrict__ scale,
                                                const float* __restrict__ shift, size_t total4)
{
    size_t idx = (size_t)blockIdx.x * 256 + threadIdx.x;
    if (idx >= total4) return;
    size_t off = idx * 4;
    int c = (int)(off & 127);
    float4 v = *(const float4*)(h + off);
    float4 sc = *(const float4*)(scale + c);
    float4 sh = *(const float4*)(shift + c);
    v.x = mishf(v.x * sc.x + sh.x);
    v.y = mishf(v.y * sc.y + sh.y);
    v.z = mishf(v.z * sc.z + sh.z);
    v.w = mishf(v.w * sc.w + sh.w);
    *(float4*)(h + off) = v;
}

// ---------------- host ----------------
extern "C" void kernel_launch(void* const* d_in, const int* in_sizes, int n_in,
                              void* d_out, int out_size, void* d_ws, size_t ws_size,
                              hipStream_t stream)
{
    (void)n_in; (void)out_size; (void)ws_size;
    const float* x       = (const float*)d_in[0];
    const float* coords  = (const float*)d_in[1];
    const int*   ei      = (const int*)d_in[2];
    const int*   bond    = (const int*)d_in[3];
    const float* W_nb    = (const float*)d_in[4];
    const float* b_nb    = (const float*)d_in[5];
    const float* W_nout  = (const float*)d_in[6];
    const float* b_nout  = (const float*)d_in[7];
    const float* conv_w  = (const float*)d_in[8];
    const float* conv_b  = (const float*)d_in[9];
    const float* W_el    = (const float*)d_in[10];
    const float* b_el    = (const float*)d_in[11];
    const float* W_eout  = (const float*)d_in[12];
    const float* b_eout  = (const float*)d_in[13];
    const float* W_coord = (const float*)d_in[14];
    const float* b_coord = (const float*)d_in[15];
    const float* W_pair  = (const float*)d_in[16];
    const float* b_pair  = (const float*)d_in[17];
    const float* W_sout  = (const float*)d_in[18];
    const float* b_sout  = (const float*)d_in[19];
    const float* W_init  = (const float*)d_in[20];
    const float* feat_lin= (const float*)d_in[21];
    const float* W_att   = (const float*)d_in[22];
    const float* W_agg   = (const float*)d_in[23];
    const float* gamma   = (const float*)d_in[24];
    const float* beta    = (const float*)d_in[25];

    const int N = in_sizes[0] / DD;     // 50000
    const int E = in_sizes[3];          // 800000
    const size_t ND = (size_t)N * DD;
    const int SUB = DD * DD;            // 128*128 sub-matrix stride

    // ---- workspace layout (bump allocator, 64B aligned) ----
    char* base = (char*)d_ws;
    size_t off = 0;
    auto alloc = [&](size_t bytes) -> char* {
        char* p = base + off;
        off = (off + bytes + 63) & ~(size_t)63;
        return p;
    };
    float* S[8];
    for (int i = 0; i < 8; i++) S[i] = (float*)alloc(ND * 4);
    int*   csr_src = (int*)alloc((size_t)E * 4);
    float* csr_w   = (float*)alloc((size_t)E * 4);
    float* csr_d2  = (float*)alloc((size_t)E * 4);
    int*   deg     = (int*)alloc((size_t)N * 4);
    int*   rowptr  = (int*)alloc((size_t)(N + 1) * 4);
    int*   cursor  = (int*)alloc((size_t)N * 4);
    float* s_arr   = (float*)alloc((size_t)N * 4);
    float* bnsums  = (float*)alloc(256 * 4);
    float* bnscale = (float*)alloc(128 * 4);
    float* bnshift = (float*)alloc(128 * 4);

    float* hout = (float*)d_out;

    const dim3 blk(256);
    const dim3 gG((N + 127) / 128);
    const dim3 gE((E + 255) / 256);
    const dim3 gNode((N + 3) / 4);
    const size_t total4 = ND / 4;
    const dim3 gElem((unsigned)((total4 + 255) / 256));

    // weight sub-views ([2D,D] row-major: top D rows contiguous first)
    const float* Wnb_t = W_nb;          const float* Wnb_s = W_nb + SUB;
    const float* Wel_t = W_el;          const float* Wel_s = W_el + SUB;
    const float* Wc_t  = W_coord;       const float* Wc_s  = W_coord + SUB;
    const float* Ws_t  = W_sout;        const float* Ws_b  = W_sout + SUB;
    const float* Wa_t  = W_att;         const float* Wa_b  = W_att + SUB;

    // ---- stage A: node-level projections (edge matmuls factored to nodes) ----
    gemm128<0,false,false,false,false><<<gG, blk, 0, stream>>>(x, Wnb_t, S[0], N, nullptr, nullptr, nullptr, nullptr); // A_t
    gemm128<0,false,false,false,false><<<gG, blk, 0, stream>>>(x, Wnb_s, S[1], N, nullptr, nullptr, nullptr, nullptr); // A_s
    gemm128<0,false,false,false,false><<<gG, blk, 0, stream>>>(x, Wel_t, S[2], N, nullptr, nullptr, nullptr, nullptr); // B_t
    gemm128<0,false,false,false,false><<<gG, blk, 0, stream>>>(x, Wel_s, S[3], N, nullptr, nullptr, nullptr, nullptr); // B_s
    gemm128<0,false,false,false,false><<<gG, blk, 0, stream>>>(x, Wc_t,  S[4], N, nullptr, nullptr, nullptr, nullptr); // Ct

    // ---- stage B: CSR by dst (counting sort, rebuilt every launch) ----
    hipMemsetAsync(deg, 0, (size_t)N * 4, stream);
    hist_kernel<<<gE, blk, 0, stream>>>(ei, deg, E);
    scan_kernel<<<1, 1024, 0, stream>>>(deg, rowptr, cursor, N);
    scatter_kernel<<<gE, blk, 0, stream>>>(ei, bond, conv_w, conv_b, coords, cursor,
                                           csr_src, csr_w, csr_d2, E);

    // ---- stage C: per-node aggregation (no atomics) ----
    edge_agg<<<gNode, blk, 0, stream>>>(S[0], S[1], S[2], S[3], x, rowptr, csr_src, csr_w, csr_d2,
                                        b_nb, b_el, S[5], S[6], S[7], s_arr, N);
    // S5=P_node, S6=P_edge, S7=z

    // ---- stage D: node-level pipeline ----
    // Qagg = z@Wc_s + s_i*Ct + deg_i*b_coord  -> S0
    gemm128<0,true,true,true,true><<<gG, blk, 0, stream>>>(S[7], Wc_s, S[0], N, S[4], s_arr, b_coord, deg);
    // Q = mish(Qagg@W_pair + b_pair) -> S1
    gemm128<1,false,false,true,false><<<gG, blk, 0, stream>>>(S[0], W_pair, S[1], N, nullptr, nullptr, b_pair, nullptr);
    // f_node = mish(P_node@W_nout + b_nout) -> S2
    gemm128<1,false,false,true,false><<<gG, blk, 0, stream>>>(S[5], W_nout, S[2], N, nullptr, nullptr, b_nout, nullptr);
    // f_edge = mish(P_edge@W_eout + b_eout) -> S3
    gemm128<1,false,false,true,false><<<gG, blk, 0, stream>>>(S[6], W_eout, S[3], N, nullptr, nullptr, b_eout, nullptr);
    // tmp = x@Ws_t -> S4
    gemm128<0,false,false,false,false><<<gG, blk, 0, stream>>>(x, Ws_t, S[4], N, nullptr, nullptr, nullptr, nullptr);
    // f_struct = mish(Q@Ws_b + tmp + b_sout) -> S5
    gemm128<1,true,false,true,false><<<gG, blk, 0, stream>>>(S[1], Ws_b, S[5], N, S[4], nullptr, b_sout, nullptr);
    // lin2 = mish(mish(x@W_init)) -> S6
    gemm128<2,false,false,false,false><<<gG, blk, 0, stream>>>(x, W_init, S[6], N, nullptr, nullptr, nullptr, nullptr);
    // e0 = lin2@Wa_t -> S7
    gemm128<0,false,false,false,false><<<gG, blk, 0, stream>>>(S[6], Wa_t, S[7], N, nullptr, nullptr, nullptr, nullptr);

    // per-path attention logits: e_f = mish2(f_f@FL_f)@Wa_b + e0
    // f=0 (f_node=S2): lf2->S6, e1->S0
    gemm128<2,false,false,false,false><<<gG, blk, 0, stream>>>(S[2], feat_lin + 0 * SUB, S[6], N, nullptr, nullptr, nullptr, nullptr);
    gemm128<0,true,false,false,false><<<gG, blk, 0, stream>>>(S[6], Wa_b, S[0], N, S[7], nullptr, nullptr, nullptr);
    // f=1 (f_edge=S3): lf2->S6, e2->S4
    gemm128<2,false,false,false,false><<<gG, blk, 0, stream>>>(S[3], feat_lin + 1 * SUB, S[6], N, nullptr, nullptr, nullptr, nullptr);
    gemm128<0,true,false,false,false><<<gG, blk, 0, stream>>>(S[6], Wa_b, S[4], N, S[7], nullptr, nullptr, nullptr);
    // f=2 (f_struct=S5): lf2->S6, e3->S1
    gemm128<2,false,false,false,false><<<gG, blk, 0, stream>>>(S[5], feat_lin + 2 * SUB, S[6], N, nullptr, nullptr, nullptr, nullptr);
    gemm128<0,true,false,false,false><<<gG, blk, 0, stream>>>(S[6], Wa_b, S[1], N, S[7], nullptr, nullptr, nullptr);

    // att = softmax_f(e)*f  -> S6
    att_kernel<<<gElem, blk, 0, stream>>>(S[0], S[4], S[1], S[2], S[3], S[5], S[6], total4);
    // h_agg = att@W_agg -> d_out
    gemm128<0,false,false,false,false><<<gG, blk, 0, stream>>>(S[6], W_agg, hout, N, nullptr, nullptr, nullptr, nullptr);

    // ---- batchnorm (training stats) + final mish, in-place on d_out ----
    hipMemsetAsync(bnsums, 0, 256 * 4, stream);
    bn_stats<<<512, blk, 0, stream>>>(hout, bnsums, N);
    bn_finalize<<<1, 128, 0, stream>>>(bnsums, gamma, beta, bnscale, bnshift, 1.0f / (float)N);
    bn_apply<<<gElem, blk, 0, stream>>>(hout, bnscale, bnshift, total4);
}

// Round 3
// 830.217 us; speedup vs baseline: 1.5492x; 1.5492x over previous
//
#include <hip/hip_runtime.h>
#include <math.h>

#define DD 128
#define LDSS 136   // u16 LDS stride for bf16 chain0 (128 + 8 pad)
#define LDSF 132   // f32 LDS stride for split chains (128 + 4 pad)

typedef __attribute__((ext_vector_type(8))) short bf16x8;
typedef __attribute__((ext_vector_type(4))) float f32x4;
typedef unsigned short u16;
typedef unsigned int u32;

__device__ __forceinline__ u16 f2bf(float f) {
    u32 u = __builtin_bit_cast(u32, f);
    u += 0x7fffu + ((u >> 16) & 1u);   // RNE
    return (u16)(u >> 16);
}
__device__ __forceinline__ float bf2f(u16 h) {
    u32 u = ((u32)h) << 16;
    return __builtin_bit_cast(float, u);
}
__device__ __forceinline__ float mishf(float x) {
    float e = __expf(fminf(x, 15.0f));
    float n = e * (e + 2.0f);
    return x * n * __builtin_amdgcn_rcpf(n + 2.0f);
}
__device__ __forceinline__ void split8(const float* v, bf16x8& h, bf16x8& l) {
#pragma unroll
    for (int j = 0; j < 8; j++) {
        u16 hj = f2bf(v[j]);
        float r = v[j] - bf2f(hj);
        h[j] = (short)hj;
        l[j] = (short)f2bf(r);
    }
}
__device__ __forceinline__ f32x4 mfma3(bf16x8 ah, bf16x8 al, bf16x8 bh, bf16x8 bl, f32x4 acc) {
    acc = __builtin_amdgcn_mfma_f32_16x16x32_bf16(ah, bh, acc, 0, 0, 0);
    acc = __builtin_amdgcn_mfma_f32_16x16x32_bf16(al, bh, acc, 0, 0, 0);
    acc = __builtin_amdgcn_mfma_f32_16x16x32_bf16(ah, bl, acc, 0, 0, 0);
    return acc;
}

// ============ weight prep: fp32 [128,128] -> bf16 hi/lo packed B-fragment layout ============
struct WSrc { const float* p[18]; };

__global__ __launch_bounds__(256) void prep_weights(WSrc ws, u16* __restrict__ Wh, u16* __restrict__ Wl)
{
    int mat = blockIdx.x >> 3, chunk = blockIdx.x & 7;
    int t = threadIdx.x;
    int tt = chunk * 4 + (t >> 6);     // tile 0..31 (kb*8+nt)
    int lane = t & 63;
    int kb = tt >> 3, nt = tt & 7;
    const float* __restrict__ src = ws.p[mat];
    size_t doff = (size_t)mat * 16384 + ((size_t)tt * 64 + lane) * 8;
    int srow = kb * 32 + ((lane >> 4) * 8);
    int scol = nt * 16 + (lane & 15);
    u16 th[8], tl[8];
#pragma unroll
    for (int j = 0; j < 8; j++) {
        float v = src[(srow + j) * DD + scol];
        u16 h = f2bf(v);
        th[j] = h;
        tl[j] = f2bf(v - bf2f(h));
    }
    *(bf16x8*)(Wh + doff) = *(bf16x8*)th;
    *(bf16x8*)(Wl + doff) = *(bf16x8*)tl;
}

__global__ __launch_bounds__(256) void cvt_bf16(const float* __restrict__ in, u16* __restrict__ out, size_t n4)
{
    size_t i = (size_t)blockIdx.x * 256 + threadIdx.x;
    if (i >= n4) return;
    float4 v = ((const float4*)in)[i];
    ushort4 o;
    o.x = f2bf(v.x); o.y = f2bf(v.y); o.z = f2bf(v.z); o.w = f2bf(v.w);
    ((ushort4*)out)[i] = o;
}

// ============ bf16 single-precision MFMA stage (chain0 only; errors common-mode cancel) ============
template<int ACT, bool HAS_X, bool A_LDS, bool WR_LDS, int STORE>
__device__ __forceinline__ void mm_stage(
    int rowBase, int M, int wave, int lane,
    const u16* __restrict__ Ag, u16* lds,
    const u16* __restrict__ Wp,
    const u16* __restrict__ X, void* __restrict__ outp)
{
    const int lm = lane & 15;
    const int quad = lane >> 4;
    bf16x8 a[2][4];
    if (A_LDS) {
#pragma unroll
        for (int rt = 0; rt < 2; rt++) {
            int m = (wave * 2 + rt) * 16 + lm;
            const u16* p = lds + m * LDSS + quad * 8;
#pragma unroll
            for (int kb = 0; kb < 4; kb++) a[rt][kb] = *(const bf16x8*)(p + kb * 32);
        }
    } else {
#pragma unroll
        for (int rt = 0; rt < 2; rt++) {
            int row = rowBase + (wave * 2 + rt) * 16 + lm;
            if (row >= M) row = M - 1;
            const u16* p = Ag + (size_t)row * DD + quad * 8;
#pragma unroll
            for (int kb = 0; kb < 4; kb++) a[rt][kb] = *(const bf16x8*)(p + kb * 32);
        }
    }
    f32x4 acc[2][8];
#pragma unroll
    for (int rt = 0; rt < 2; rt++)
#pragma unroll
        for (int nt = 0; nt < 8; nt++) { f32x4 z4 = {0.f, 0.f, 0.f, 0.f}; acc[rt][nt] = z4; }
#pragma unroll
    for (int kb = 0; kb < 4; kb++)
#pragma unroll
        for (int nt = 0; nt < 8; nt++) {
            bf16x8 b = *(const bf16x8*)(Wp + (((size_t)kb * 8 + nt) * 64 + lane) * 8);
            acc[0][nt] = __builtin_amdgcn_mfma_f32_16x16x32_bf16(a[0][kb], b, acc[0][nt], 0, 0, 0);
            acc[1][nt] = __builtin_amdgcn_mfma_f32_16x16x32_bf16(a[1][kb], b, acc[1][nt], 0, 0, 0);
        }
    if (WR_LDS) __syncthreads();
#pragma unroll
    for (int rt = 0; rt < 2; rt++) {
        int trBase = (wave * 2 + rt) * 16 + quad * 4;
#pragma unroll
        for (int r = 0; r < 4; r++) {
            int tr = trBase + r;
            int grow = rowBase + tr;
            bool inb = grow < M;
            int crow = inb ? grow : (M - 1);
#pragma unroll
            for (int nt = 0; nt < 8; nt++) {
                int col = nt * 16 + lm;
                float v = acc[rt][nt][r];
                if (HAS_X) v += bf2f(X[(size_t)crow * DD + col]);
                if (ACT >= 1) v = mishf(v);
                if (ACT == 2) v = mishf(v);
                if (WR_LDS) lds[tr * LDSS + col] = f2bf(v);
                if (STORE == 1 && inb) ((u16*)outp)[(size_t)grow * DD + col] = f2bf(v);
            }
        }
    }
    if (WR_LDS) __syncthreads();
}

// ============ split-precision MFMA stage (64-row blocks, wave-private LDS) ============
// C = ACT(A@W + [XB bf16] + [rs*CT fp32] + [bv*]bias)
template<int ACT, bool HAS_XB, bool HAS_CT, bool HAS_BIAS, bool HAS_BV, bool A_LDS, bool WR_LDS, int STORE>
__device__ __forceinline__ void mm32_stage(
    int rowBase, int M, int wave, int lane,
    const float* __restrict__ Ag, float* lds,
    const u16* __restrict__ Wh, const u16* __restrict__ Wl,
    const u16* __restrict__ XB,
    const float* __restrict__ CT, const float* __restrict__ rs,
    const float* __restrict__ bias, const int* __restrict__ bv,
    void* __restrict__ outp)
{
    const int lm = lane & 15;
    const int quad = lane >> 4;
    bf16x8 ah[4], al[4];
    {
        const float* p;
        if (A_LDS) {
            p = lds + (wave * 16 + lm) * LDSF + quad * 8;
        } else {
            int row = rowBase + wave * 16 + lm;
            if (row >= M) row = M - 1;
            p = Ag + (size_t)row * DD + quad * 8;
        }
#pragma unroll
        for (int kb = 0; kb < 4; kb++) {
            float tmp[8];
            *(float4*)tmp       = *(const float4*)(p + kb * 32);
            *(float4*)(tmp + 4) = *(const float4*)(p + kb * 32 + 4);
            split8(tmp, ah[kb], al[kb]);
        }
    }
    f32x4 acc[8];
#pragma unroll
    for (int nt = 0; nt < 8; nt++) { f32x4 z4 = {0.f, 0.f, 0.f, 0.f}; acc[nt] = z4; }
#pragma unroll
    for (int kb = 0; kb < 4; kb++)
#pragma unroll
        for (int nt = 0; nt < 8; nt++) {
            size_t boff = (((size_t)kb * 8 + nt) * 64 + lane) * 8;
            bf16x8 bh = *(const bf16x8*)(Wh + boff);
            bf16x8 bl = *(const bf16x8*)(Wl + boff);
            acc[nt] = mfma3(ah[kb], al[kb], bh, bl, acc[nt]);
        }
    // LDS is wave-private (A rows == C rows == this wave's 16-row band): no barrier needed
#pragma unroll
    for (int r = 0; r < 4; r++) {
        int tr = wave * 16 + quad * 4 + r;
        int grow = rowBase + tr;
        bool inb = grow < M;
        int crow = inb ? grow : (M - 1);
        float rsv = HAS_CT ? rs[crow] : 0.0f;
        float bvf = HAS_BV ? (float)bv[crow] : 1.0f;
#pragma unroll
        for (int nt = 0; nt < 8; nt++) {
            int col = nt * 16 + lm;
            float v = acc[nt][r];
            if (HAS_XB) v += bf2f(XB[(size_t)crow * DD + col]);
            if (HAS_CT) v += rsv * CT[(size_t)crow * DD + col];
            if (HAS_BIAS) v += bvf * bias[col];
            if (ACT >= 1) v = mishf(v);
            if (ACT == 2) v = mishf(v);
            if (WR_LDS) lds[tr * LDSF + col] = v;
            if (STORE == 1 && inb) ((u16*)outp)[(size_t)grow * DD + col] = f2bf(v);
            if (STORE == 2 && inb) ((float*)outp)[(size_t)grow * DD + col] = v;
        }
    }
}

// ============ stage A (bf16): As, Bs, xWs from xb ============
__global__ __launch_bounds__(256) void stageA_kernel(
    const u16* __restrict__ xb, const u16* __restrict__ Wh, u16* __restrict__ out0, int M)
{
    const int wave = threadIdx.x >> 6, lane = threadIdx.x & 63;
    const int lm = lane & 15, quad = lane >> 4;
    const int rowBase = blockIdx.x * 128;
    const size_t ND = (size_t)M * DD;
    bf16x8 a[2][4];
#pragma unroll
    for (int rt = 0; rt < 2; rt++) {
        int row = rowBase + (wave * 2 + rt) * 16 + lm;
        if (row >= M) row = M - 1;
        const u16* p = xb + (size_t)row * DD + quad * 8;
#pragma unroll
        for (int kb = 0; kb < 4; kb++) a[rt][kb] = *(const bf16x8*)(p + kb * 32);
    }
    for (int wi = 0; wi < 3; wi++) {
        const u16* Wm = Wh + (size_t)(2 * wi + 1) * 16384;   // mats 1,3,5
        f32x4 acc[2][8];
#pragma unroll
        for (int rt = 0; rt < 2; rt++)
#pragma unroll
            for (int nt = 0; nt < 8; nt++) { f32x4 z4 = {0.f, 0.f, 0.f, 0.f}; acc[rt][nt] = z4; }
#pragma unroll
        for (int kb = 0; kb < 4; kb++)
#pragma unroll
            for (int nt = 0; nt < 8; nt++) {
                bf16x8 b = *(const bf16x8*)(Wm + (((size_t)kb * 8 + nt) * 64 + lane) * 8);
                acc[0][nt] = __builtin_amdgcn_mfma_f32_16x16x32_bf16(a[0][kb], b, acc[0][nt], 0, 0, 0);
                acc[1][nt] = __builtin_amdgcn_mfma_f32_16x16x32_bf16(a[1][kb], b, acc[1][nt], 0, 0, 0);
            }
        u16* out = out0 + (size_t)wi * ND;
#pragma unroll
        for (int rt = 0; rt < 2; rt++) {
            int trBase = (wave * 2 + rt) * 16 + quad * 4;
#pragma unroll
            for (int r = 0; r < 4; r++) {
                int grow = rowBase + trBase + r;
                if (grow >= M) continue;
#pragma unroll
                for (int nt = 0; nt < 8; nt++)
                    out[(size_t)grow * DD + nt * 16 + lm] = f2bf(acc[rt][nt][r]);
            }
        }
    }
}

// ============ stage A32 (split): At, Bt, Ct fp32 from fp32 x ============
__global__ __launch_bounds__(256) void stageA32_kernel(
    const float* __restrict__ x, const u16* __restrict__ Wh, const u16* __restrict__ Wl,
    float* __restrict__ out0, int M)
{
    const int wave = threadIdx.x >> 6, lane = threadIdx.x & 63;
    const int lm = lane & 15, quad = lane >> 4;
    const int rowBase = blockIdx.x * 64;
    const size_t ND = (size_t)M * DD;
    bf16x8 ah[4], al[4];
    {
        int row = rowBase + wave * 16 + lm;
        if (row >= M) row = M - 1;
        const float* p = x + (size_t)row * DD + quad * 8;
#pragma unroll
        for (int kb = 0; kb < 4; kb++) {
            float tmp[8];
            *(float4*)tmp       = *(const float4*)(p + kb * 32);
            *(float4*)(tmp + 4) = *(const float4*)(p + kb * 32 + 4);
            split8(tmp, ah[kb], al[kb]);
        }
    }
    for (int wi = 0; wi < 3; wi++) {
        size_t mo = (size_t)(2 * wi) * 16384;    // mats 0,2,4
        f32x4 acc[8];
#pragma unroll
        for (int nt = 0; nt < 8; nt++) { f32x4 z4 = {0.f, 0.f, 0.f, 0.f}; acc[nt] = z4; }
#pragma unroll
        for (int kb = 0; kb < 4; kb++)
#pragma unroll
            for (int nt = 0; nt < 8; nt++) {
                size_t boff = mo + (((size_t)kb * 8 + nt) * 64 + lane) * 8;
                bf16x8 bh = *(const bf16x8*)(Wh + boff);
                bf16x8 bl = *(const bf16x8*)(Wl + boff);
                acc[nt] = mfma3(ah[kb], al[kb], bh, bl, acc[nt]);
            }
        float* out = out0 + (size_t)wi * ND;
#pragma unroll
        for (int r = 0; r < 4; r++) {
            int grow = rowBase + wave * 16 + quad * 4 + r;
            if (grow >= M) continue;
#pragma unroll
            for (int nt = 0; nt < 8; nt++)
                out[(size_t)grow * DD + nt * 16 + lm] = acc[nt][r];
        }
    }
}

// ============ chain kernels ============
__global__ __launch_bounds__(256) void chain0_kernel(
    const u16* __restrict__ xb, const u16* __restrict__ Wh, u16* __restrict__ e0, int M)
{
    __shared__ u16 lds[128 * LDSS];
    int wave = threadIdx.x >> 6, lane = threadIdx.x & 63;
    int rowBase = blockIdx.x * 128;
    mm_stage<2,false,false,true,0>(rowBase, M, wave, lane, xb, lds, Wh + 6*16384, nullptr, nullptr);
    mm_stage<0,false,true,false,1>(rowBase, M, wave, lane, nullptr, lds, Wh + 7*16384, nullptr, e0);
}

__global__ __launch_bounds__(256) void chainNE32_kernel(
    const float* __restrict__ P, const float* __restrict__ b_out,
    const u16* __restrict__ Wh, const u16* __restrict__ Wl, int mOut, int mFL,
    const u16* __restrict__ e0, u16* __restrict__ f_out, float* __restrict__ e_out, int M)
{
    __shared__ float lds[64 * LDSF];
    int wave = threadIdx.x >> 6, lane = threadIdx.x & 63;
    int rowBase = blockIdx.x * 64;
    // f = mish(P@W_out + b_out) -> LDS fp32 + global bf16
    mm32_stage<1,false,false,true,false,false,true,1>(rowBase, M, wave, lane, P, lds,
        Wh + (size_t)mOut*16384, Wl + (size_t)mOut*16384, nullptr, nullptr, nullptr, b_out, nullptr, f_out);
    // l = mish2(f@FL) -> LDS
    mm32_stage<2,false,false,false,false,true,true,0>(rowBase, M, wave, lane, nullptr, lds,
        Wh + (size_t)mFL*16384, Wl + (size_t)mFL*16384, nullptr, nullptr, nullptr, nullptr, nullptr, nullptr);
    // e = l@Wa_b + e0 -> fp32 global
    mm32_stage<0,true,false,false,false,true,false,2>(rowBase, M, wave, lane, nullptr, lds,
        Wh + 16*16384, Wl + 16*16384, e0, nullptr, nullptr, nullptr, nullptr, e_out);
}

__global__ __launch_bounds__(256) void chainS32_kernel(
    const float* __restrict__ z, const float* __restrict__ Ct, const float* __restrict__ s_arr,
    const int* __restrict__ deg, const float* __restrict__ b_coord, const float* __restrict__ b_pair,
    const u16* __restrict__ xWs, const float* __restrict__ b_sout,
    const u16* __restrict__ Wh, const u16* __restrict__ Wl, const u16* __restrict__ e0,
    u16* __restrict__ f3, float* __restrict__ e3, int M)
{
    __shared__ float lds[64 * LDSF];
    int wave = threadIdx.x >> 6, lane = threadIdx.x & 63;
    int rowBase = blockIdx.x * 64;
    // Qagg = z@Wc_s + s*Ct + deg*b_coord -> LDS
    mm32_stage<0,false,true,true,true,false,true,0>(rowBase, M, wave, lane, z, lds,
        Wh + 8*16384, Wl + 8*16384, nullptr, Ct, s_arr, b_coord, deg, nullptr);
    // Q = mish(Qagg@W_pair + b_pair) -> LDS
    mm32_stage<1,false,false,true,false,true,true,0>(rowBase, M, wave, lane, nullptr, lds,
        Wh + 9*16384, Wl + 9*16384, nullptr, nullptr, nullptr, b_pair, nullptr, nullptr);
    // f_struct = mish(Q@Ws_b + xWs + b_sout) -> LDS + global bf16
    mm32_stage<1,true,false,true,false,true,true,1>(rowBase, M, wave, lane, nullptr, lds,
        Wh + 10*16384, Wl + 10*16384, xWs, nullptr, nullptr, b_sout, nullptr, f3);
    // l2 = mish2(f_struct@FL2) -> LDS
    mm32_stage<2,false,false,false,false,true,true,0>(rowBase, M, wave, lane, nullptr, lds,
        Wh + 15*16384, Wl + 15*16384, nullptr, nullptr, nullptr, nullptr, nullptr, nullptr);
    // e3 = l2@Wa_b + e0 -> fp32 global
    mm32_stage<0,true,false,false,false,true,false,2>(rowBase, M, wave, lane, nullptr, lds,
        Wh + 16*16384, Wl + 16*16384, e0, nullptr, nullptr, nullptr, nullptr, e3);
}

// ============ softmax-attention combine fused with @W_agg (split-A) ============
__global__ __launch_bounds__(256) void attagg_kernel(
    const float* __restrict__ e1, const float* __restrict__ e2, const float* __restrict__ e3,
    const u16* __restrict__ f1, const u16* __restrict__ f2, const u16* __restrict__ f3,
    const u16* __restrict__ Wh, const u16* __restrict__ Wl, float* __restrict__ out, int M)
{
    int wave = threadIdx.x >> 6, lane = threadIdx.x & 63;
    int lm = lane & 15, quad = lane >> 4;
    int rowBase = blockIdx.x * 128;
    bf16x8 ah[2][4], al[2][4];
#pragma unroll
    for (int rt = 0; rt < 2; rt++) {
        int row = rowBase + (wave * 2 + rt) * 16 + lm;
        if (row >= M) row = M - 1;
        size_t base = (size_t)row * DD + quad * 8;
#pragma unroll
        for (int kb = 0; kb < 4; kb++) {
            size_t off = base + kb * 32;
            float a1[8], a2[8], a3[8];
            *(float4*)a1 = *(const float4*)(e1 + off); *(float4*)(a1+4) = *(const float4*)(e1 + off + 4);
            *(float4*)a2 = *(const float4*)(e2 + off); *(float4*)(a2+4) = *(const float4*)(e2 + off + 4);
            *(float4*)a3 = *(const float4*)(e3 + off); *(float4*)(a3+4) = *(const float4*)(e3 + off + 4);
            bf16x8 w1 = *(const bf16x8*)(f1 + off);
            bf16x8 w2 = *(const bf16x8*)(f2 + off);
            bf16x8 w3 = *(const bf16x8*)(f3 + off);
            float att[8];
#pragma unroll
            for (int j = 0; j < 8; j++) {
                float x1 = a1[j], x2 = a2[j], x3 = a3[j];
                float m = fmaxf(fmaxf(x1, x2), x3);
                float p1 = __expf(x1 - m), p2 = __expf(x2 - m), p3 = __expf(x3 - m);
                att[j] = (p1 * bf2f((u16)w1[j]) + p2 * bf2f((u16)w2[j]) + p3 * bf2f((u16)w3[j]))
                         * __builtin_amdgcn_rcpf(p1 + p2 + p3);
            }
            split8(att, ah[rt][kb], al[rt][kb]);
        }
    }
    f32x4 acc[2][8];
#pragma unroll
    for (int rt = 0; rt < 2; rt++)
#pragma unroll
        for (int nt = 0; nt < 8; nt++) { f32x4 z4 = {0.f, 0.f, 0.f, 0.f}; acc[rt][nt] = z4; }
#pragma unroll
    for (int kb = 0; kb < 4; kb++)
#pragma unroll
        for (int nt = 0; nt < 8; nt++) {
            size_t boff = (((size_t)kb * 8 + nt) * 64 + lane) * 8;
            bf16x8 bh = *(const bf16x8*)(Wh + boff);
            bf16x8 bl = *(const bf16x8*)(Wl + boff);
            acc[0][nt] = mfma3(ah[0][kb], al[0][kb], bh, bl, acc[0][nt]);
            acc[1][nt] = mfma3(ah[1][kb], al[1][kb], bh, bl, acc[1][nt]);
        }
#pragma unroll
    for (int rt = 0; rt < 2; rt++) {
        int trBase = (wave * 2 + rt) * 16 + quad * 4;
#pragma unroll
        for (int r = 0; r < 4; r++) {
            int grow = rowBase + trBase + r;
            if (grow >= M) continue;
#pragma unroll
            for (int nt = 0; nt < 8; nt++)
                out[(size_t)grow * DD + nt * 16 + lm] = acc[rt][nt][r];
        }
    }
}

// ============ CSR build (counting sort by dst) ============
__global__ __launch_bounds__(256) void hist_kernel(const int* __restrict__ ei, int* __restrict__ deg, int E)
{
    int e = blockIdx.x * 256 + threadIdx.x;
    if (e < E) atomicAdd(&deg[ei[E + e]], 1);
}

__global__ __launch_bounds__(1024) void scan_kernel(const int* __restrict__ deg,
                                                    int* __restrict__ rowptr,
                                                    int* __restrict__ cursor, int N)
{
    __shared__ int sums[1024];
    int t = threadIdx.x;
    int CH = (N + 1023) / 1024;
    int base = t * CH;
    int local = 0;
    for (int i = 0; i < CH; i++) {
        int idx = base + i;
        if (idx < N) local += deg[idx];
    }
    sums[t] = local;
    __syncthreads();
    for (int off = 1; off < 1024; off <<= 1) {
        int v = sums[t];
        int u = (t >= off) ? sums[t - off] : 0;
        __syncthreads();
        sums[t] = v + u;
        __syncthreads();
    }
    int run = (t == 0) ? 0 : sums[t - 1];
    for (int i = 0; i < CH; i++) {
        int idx = base + i;
        if (idx < N) {
            rowptr[idx] = run;
            cursor[idx] = run;
            run += deg[idx];
        }
    }
    if (t == 1023) rowptr[N] = sums[1023];
}

__global__ __launch_bounds__(256) void scatter_kernel(
    const int* __restrict__ ei, const int* __restrict__ bond,
    const float* __restrict__ conv_w, const float* __restrict__ conv_b,
    const float* __restrict__ coords, int* __restrict__ cursor,
    int* __restrict__ csr_src, float* __restrict__ csr_w, float* __restrict__ csr_d2, int E)
{
    int e = blockIdx.x * 256 + threadIdx.x;
    if (e >= E) return;
    int src = ei[e], dst = ei[E + e];
    int pos = atomicAdd(&cursor[dst], 1);
    csr_src[pos] = src;
    csr_w[pos] = conv_w[bond[e]] + conv_b[0];
    float dx = coords[src * 3 + 0] - coords[dst * 3 + 0];
    float dy = coords[src * 3 + 1] - coords[dst * 3 + 1];
    float dz = coords[src * 3 + 2] - coords[dst * 3 + 2];
    csr_d2[pos] = dx * dx + dy * dy + dz * dz;
}

// ============ per-node edge aggregation ============
__global__ __launch_bounds__(256) void edge_agg(
    const float* __restrict__ At, const float* __restrict__ Bt,   // fp32 node-level
    const u16* __restrict__ As, const u16* __restrict__ Bs,       // bf16 gathered
    const float* __restrict__ xf,                                 // fp32 x gathered
    const int* __restrict__ rowptr, const int* __restrict__ csr_src,
    const float* __restrict__ csr_w, const float* __restrict__ csr_d2,
    const float* __restrict__ b_nb, const float* __restrict__ b_el,
    float* __restrict__ Pn, float* __restrict__ Pe, float* __restrict__ z,
    float* __restrict__ s_arr, int N)
{
    int wave = threadIdx.x >> 6;
    int lane = threadIdx.x & 63;
    int node = blockIdx.x * 4 + wave;
    if (node >= N) return;
    int c0 = lane * 2;
    float2 at = *(const float2*)(At + (size_t)node * DD + c0);
    float2 bt = *(const float2*)(Bt + (size_t)node * DD + c0);
    float bn0 = b_nb[c0], bn1 = b_nb[c0 + 1];
    float be0 = b_el[c0], be1 = b_el[c0 + 1];
    float accn0 = 0.f, accn1 = 0.f, acce0 = 0.f, acce1 = 0.f, accz0 = 0.f, accz1 = 0.f, ssum = 0.f;
    int beg = rowptr[node], end = rowptr[node + 1];
    for (int k = beg; k < end; k++) {
        int j = csr_src[k];
        float w = csr_w[k];
        float d2 = csr_d2[k];
        u32 ua = *(const u32*)(As + (size_t)j * DD + c0);
        u32 ub = *(const u32*)(Bs + (size_t)j * DD + c0);
        float2 xv = *(const float2*)(xf + (size_t)j * DD + c0);
        float a0 = __builtin_bit_cast(float, ua << 16), a1 = __builtin_bit_cast(float, ua & 0xffff0000u);
        float b0 = __builtin_bit_cast(float, ub << 16), b1 = __builtin_bit_cast(float, ub & 0xffff0000u);
        accn0 += mishf(at.x + a0 + bn0);
        accn1 += mishf(at.y + a1 + bn1);
        acce0 += mishf(w * (bt.x + b0) + be0);
        acce1 += mishf(w * (bt.y + b1) + be1);
        accz0 += d2 * xv.x;
        accz1 += d2 * xv.y;
        ssum += d2;
    }
    *(float2*)(Pn + (size_t)node * DD + c0) = make_float2(accn0, accn1);
    *(float2*)(Pe + (size_t)node * DD + c0) = make_float2(acce0, acce1);
    *(float2*)(z  + (size_t)node * DD + c0) = make_float2(accz0, accz1);
    if (lane == 0) s_arr[node] = ssum;
}

// ============ batchnorm ============
__global__ __launch_bounds__(256) void bn_stats(const float* __restrict__ h, float* __restrict__ sums, int N)
{
    int t = threadIdx.x;
    int col = t & 127;
    float s = 0.f, sq = 0.f;
    for (int r = blockIdx.x * 2 + (t >> 7); r < N; r += gridDim.x * 2) {
        float v = h[(size_t)r * DD + col];
        s += v; sq += v * v;
    }
    __shared__ float sh[256];
    sh[t] = s; __syncthreads();
    float s2 = (t < 128) ? (sh[t] + sh[t + 128]) : 0.f;
    __syncthreads();
    sh[t] = sq; __syncthreads();
    if (t < 128) {
        float q2 = sh[t] + sh[t + 128];
        atomicAdd(&sums[t], s2);
        atomicAdd(&sums[128 + t], q2);
    }
}

__global__ void bn_finalize(const float* __restrict__ sums, const float* __restrict__ gamma,
                            const float* __restrict__ beta, float* __restrict__ scale,
                            float* __restrict__ shift, float n_inv)
{
    int c = threadIdx.x;
    float mean = sums[c] * n_inv;
    float var = sums[128 + c] * n_inv - mean * mean;
    float inv = rsqrtf(var + 1e-5f);
    float sc = gamma[c] * inv;
    scale[c] = sc;
    shift[c] = beta[c] - mean * sc;
}

__global__ __launch_bounds__(256) void bn_apply(float* __restrict__ h, const float* __restrict__ scale,
                                                const float* __restrict__ shift, size_t total4)
{
    size_t idx = (size_t)blockIdx.x * 256 + threadIdx.x;
    if (idx >= total4) return;
    size_t off = idx * 4;
    int c = (int)(off & 127);
    float4 v = *(const float4*)(h + off);
    float4 sc = *(const float4*)(scale + c);
    float4 sh = *(const float4*)(shift + c);
    v.x = mishf(v.x * sc.x + sh.x);
    v.y = mishf(v.y * sc.y + sh.y);
    v.z = mishf(v.z * sc.z + sh.z);
    v.w = mishf(v.w * sc.w + sh.w);
    *(float4*)(h + off) = v;
}

// ============ host ============
extern "C" void kernel_launch(void* const* d_in, const int* in_sizes, int n_in,
                              void* d_out, int out_size, void* d_ws, size_t ws_size,
                              hipStream_t stream)
{
    (void)n_in; (void)out_size; (void)ws_size;
    const float* x       = (const float*)d_in[0];
    const float* coords  = (const float*)d_in[1];
    const int*   ei      = (const int*)d_in[2];
    const int*   bond    = (const int*)d_in[3];
    const float* W_nb    = (const float*)d_in[4];
    const float* b_nb    = (const float*)d_in[5];
    const float* W_nout  = (const float*)d_in[6];
    const float* b_nout  = (const float*)d_in[7];
    const float* conv_w  = (const float*)d_in[8];
    const float* conv_b  = (const float*)d_in[9];
    const float* W_el    = (const float*)d_in[10];
    const float* b_el    = (const float*)d_in[11];
    const float* W_eout  = (const float*)d_in[12];
    const float* b_eout  = (const float*)d_in[13];
    const float* W_coord = (const float*)d_in[14];
    const float* b_coord = (const float*)d_in[15];
    const float* W_pair  = (const float*)d_in[16];
    const float* b_pair  = (const float*)d_in[17];
    const float* W_sout  = (const float*)d_in[18];
    const float* b_sout  = (const float*)d_in[19];
    const float* W_init  = (const float*)d_in[20];
    const float* feat_lin= (const float*)d_in[21];
    const float* W_att   = (const float*)d_in[22];
    const float* W_agg   = (const float*)d_in[23];
    const float* gamma   = (const float*)d_in[24];
    const float* beta    = (const float*)d_in[25];

    const int N = in_sizes[0] / DD;     // 50000
    const int E = in_sizes[3];          // 800000
    const size_t ND = (size_t)N * DD;
    const int SUB = DD * DD;
    const int NB  = (N + 127) / 128;
    const int NBS = (N + 63) / 64;

    char* base = (char*)d_ws;
    size_t off = 0;
    auto alloc = [&](size_t bytes) -> char* {
        char* p = base + off;
        off = (off + bytes + 63) & ~(size_t)63;
        return p;
    };
    u16*   xb   = (u16*)alloc(ND * 2);
    u16*   bigB = (u16*)alloc(3 * ND * 2);     // As, Bs, xWs (bf16)
    u16*   As = bigB; u16* Bs = bigB + ND; u16* xWs = bigB + 2 * ND;
    float* bigF = (float*)alloc(3 * ND * 4);   // At, Bt, Ct (fp32)
    float* At = bigF; float* Bt = bigF + ND; float* Ct = bigF + 2 * ND;
    float* Pn = (float*)alloc(ND * 4);         // alias e1
    float* Pe = (float*)alloc(ND * 4);         // alias e2
    float* z  = (float*)alloc(ND * 4);         // alias e3
    u16*   e0 = (u16*)alloc(ND * 2);
    u16*   Wh = (u16*)alloc((size_t)18 * 16384 * 2);
    u16*   Wl = (u16*)alloc((size_t)18 * 16384 * 2);
    int*   csr_src = (int*)alloc((size_t)E * 4);
    float* csr_w   = (float*)alloc((size_t)E * 4);
    float* csr_d2  = (float*)alloc((size_t)E * 4);
    int*   deg     = (int*)alloc((size_t)N * 4);
    int*   rowptr  = (int*)alloc((size_t)(N + 1) * 4);
    int*   cursor  = (int*)alloc((size_t)N * 4);
    float* s_arr   = (float*)alloc((size_t)N * 4);
    float* bnsums  = (float*)alloc(256 * 4);
    float* bnscale = (float*)alloc(128 * 4);
    float* bnshift = (float*)alloc(128 * 4);

    float* hout = (float*)d_out;
    // aliases: chains read source rows (own 64/128-row band) before writing the same band
    float* e1 = Pn; float* e2 = Pe; float* e3 = z;
    u16* f1 = (u16*)At; u16* f2 = (u16*)Bt; u16* f3 = (u16*)Ct;   // At/Bt/Ct dead after edge_agg/chainS-stage1

    WSrc wsrc;
    wsrc.p[0] = W_nb;            wsrc.p[1] = W_nb + SUB;
    wsrc.p[2] = W_el;            wsrc.p[3] = W_el + SUB;
    wsrc.p[4] = W_coord;         wsrc.p[5] = W_sout;
    wsrc.p[6] = W_init;          wsrc.p[7] = W_att;
    wsrc.p[8] = W_coord + SUB;   wsrc.p[9] = W_pair;
    wsrc.p[10] = W_sout + SUB;   wsrc.p[11] = W_nout;
    wsrc.p[12] = W_eout;         wsrc.p[13] = feat_lin;
    wsrc.p[14] = feat_lin + SUB; wsrc.p[15] = feat_lin + 2 * SUB;
    wsrc.p[16] = W_att + SUB;    wsrc.p[17] = W_agg;

    const dim3 blk(256);
    const dim3 gE((E + 255) / 256);
    const size_t total4 = ND / 4;
    const dim3 gElem((unsigned)((total4 + 255) / 256));

    prep_weights<<<dim3(18 * 8), blk, 0, stream>>>(wsrc, Wh, Wl);
    cvt_bf16<<<gElem, blk, 0, stream>>>(x, xb, total4);

    stageA_kernel<<<NB, blk, 0, stream>>>(xb, Wh, bigB, N);
    stageA32_kernel<<<NBS, blk, 0, stream>>>(x, Wh, Wl, bigF, N);
    chain0_kernel<<<NB, blk, 0, stream>>>(xb, Wh, e0, N);

    hipMemsetAsync(deg, 0, (size_t)N * 4, stream);
    hist_kernel<<<gE, blk, 0, stream>>>(ei, deg, E);
    scan_kernel<<<1, 1024, 0, stream>>>(deg, rowptr, cursor, N);
    scatter_kernel<<<gE, blk, 0, stream>>>(ei, bond, conv_w, conv_b, coords, cursor,
                                           csr_src, csr_w, csr_d2, E);

    edge_agg<<<(N + 3) / 4, blk, 0, stream>>>(At, Bt, As, Bs, x, rowptr, csr_src, csr_w, csr_d2,
                                              b_nb, b_el, Pn, Pe, z, s_arr, N);

    chainNE32_kernel<<<NBS, blk, 0, stream>>>(Pn, b_nout, Wh, Wl, 11, 13, e0, f1, e1, N);
    chainNE32_kernel<<<NBS, blk, 0, stream>>>(Pe, b_eout, Wh, Wl, 12, 14, e0, f2, e2, N);
    chainS32_kernel<<<NBS, blk, 0, stream>>>(z, Ct, s_arr, deg, b_coord, b_pair, xWs, b_sout,
                                             Wh, Wl, e0, f3, e3, N);

    attagg_kernel<<<NB, blk, 0, stream>>>(e1, e2, e3, f1, f2, f3, Wh + 17*16384, Wl + 17*16384, hout, N);

    hipMemsetAsync(bnsums, 0, 256 * 4, stream);
    bn_stats<<<512, blk, 0, stream>>>(hout, bnsums, N);
    bn_finalize<<<1, 128, 0, stream>>>(bnsums, gamma, beta, bnscale, bnshift, 1.0f / (float)N);
    bn_apply<<<gElem, blk, 0, stream>>>(hout, bnscale, bnshift, total4);
}